// Round 7
// baseline (237.316 us; speedup 1.0000x reference)
//
#include <hip/hip_runtime.h>
#include <hip/hip_bf16.h>

typedef __attribute__((ext_vector_type(4))) float f32x4;
typedef __attribute__((ext_vector_type(8))) short bf16x8;

#define H 1024        // hidden / K
#define NTOT 1280     // nq*64 + nkv*64*2
#define BM 256
#define BN 128
#define BK 64
#define NKT 16        // H / BK
#define NTILES 10     // NTOT / BN

static __device__ __forceinline__ unsigned short f2bf(float f) {
    __hip_bfloat16 b = __float2bfloat16(f);
    return __builtin_bit_cast(unsigned short, b);
}

#define GLOAD_LDS16(g, l)                                                     \
    __builtin_amdgcn_global_load_lds(                                         \
        (const __attribute__((address_space(1))) void*)(g),                   \
        (__attribute__((address_space(3))) void*)(l), 16, 0, 0)

// ---------------------------------------------------------------------------
// Kernel 1: Bt[n][k] = bf16((1+lnw[k]) * W[k][n]) via LDS transpose tile
// (both global sides coalesced; [64][65] pad = conflict-free).
// ---------------------------------------------------------------------------
__global__ __launch_bounds__(256) void k_wprep(const float* __restrict__ wq,
                                               const float* __restrict__ wk,
                                               const float* __restrict__ wv,
                                               const float* __restrict__ lnw,
                                               __hip_bfloat16* __restrict__ Bt) {
    __shared__ float l[64][65];
    const int t = threadIdx.x;
    const int kt = blockIdx.x & 15;          // 16 k-tiles
    const int ntl = blockIdx.x >> 4;         // 20 n-tiles
    const int k0 = kt * 64, n0 = ntl * 64;
    const float* src; int ldn, nb;
    if (n0 < 1024)      { src = wq; ldn = 1024; nb = n0; }
    else if (n0 < 1152) { src = wk; ldn = 128;  nb = n0 - 1024; }
    else                { src = wv; ldn = 128;  nb = n0 - 1152; }
    const int nl = t & 63, kl = t >> 6;
#pragma unroll
    for (int i = 0; i < 16; ++i) {
        const int k = kl + i * 4;
        l[k][nl] = (1.0f + lnw[k0 + k]) * src[(size_t)(k0 + k) * ldn + nb + nl];
    }
    __syncthreads();
    const int k2 = t & 63, n2 = t >> 6;
#pragma unroll
    for (int i = 0; i < 16; ++i) {
        const int n = n2 + i * 4;
        Bt[(size_t)(n0 + n) * 1024 + k0 + k2] = __float2bfloat16(l[k2][n]);
    }
}

// ---------------------------------------------------------------------------
// Kernel 2: FUSED RMSNorm + QKV GEMM.
// out = diag(rsqrt(mean(x^2)+eps)) . (bf16(x) @ Bt^T); scale commutes with
// the linear map -> applied in epilogue; sum(x^2) accumulated during staging.
// BM=256 BN=128 BK=64, 8 waves (2M x 4N), ring-2 LDS 96KB, T2 both-sides
// swizzle, quadrant-retire staging pipeline, counted vmcnt(6), XCD chunking,
// grid 1280 = 5.0 exact rounds. acc[8][2]=64 AGPR -> ~190 VGPR headroom at
// the 256-reg / 2-waves-per-SIMD cap (the R5/R6 failure was this ledger).
// A quarters (64 rows each): {0,2} read in P1, {1,3} read in P2.
//   P1: cvt13(prev->buf^1) | issue A{0,2}(kt+2) | 12 frag reads | bar | MFMA16
//   P2: cvt02(->buf) | issue A{1,3}(kt+2) | stage B(kt+2) | 8 frag reads |
//       bar | MFMA16 | vmcnt(6) | bar
// ---------------------------------------------------------------------------
__global__ __launch_bounds__(512, 2) void k_gemm(const float* __restrict__ X,
                                                 const __hip_bfloat16* __restrict__ Bt,
                                                 float* __restrict__ out, int rows) {
    __shared__ __align__(16) char smem[98304];  // 2 bufs x (A 32KB | B 16KB)
    __shared__ float s_lds[BM];

    const int tid = threadIdx.x;
    const int lane = tid & 63;
    const int wid = tid >> 6;
    const int wm = wid >> 2;   // 0..1 (128 rows each)
    const int wn = wid & 3;    // 0..3 (32 cols each)

    // XCD chunk swizzle (1280 % 8 == 0), nt fastest: x-strip + Bt stay in XCD L2
    const int cpx = gridDim.x >> 3;                 // 160
    const int wg = (blockIdx.x & 7) * cpx + (blockIdx.x >> 3);
    const int nt = wg % NTILES;
    const int mt = wg / NTILES;
    const size_t m0 = (size_t)mt * BM;

    // ---- A staging: thread t covers row r=t>>3 of each 64-row quarter,
    //      fp32 cols (t&7)*8..+8. LDS write swizzled ^((r&7)<<4).
    const int r = tid >> 3;
    const float* xb = X + (m0 + r) * (size_t)H + (tid & 7) * 8;
    const int awz = ((tid & 7) * 16) ^ ((r & 7) << 4);

    // ---- B staging: 2 gload_lds per thread (rows t>>3 and 64+t>>3),
    //      source col pre-swizzled (both-sides involution).
    const char* bG0 = (const char*)Bt + ((size_t)nt * BN + r) * (size_t)(H * 2)
                      + (((tid & 7) * 16) ^ ((r & 7) << 4));
    const char* bG1 = bG0 + (size_t)64 * (H * 2);

    float4 va_a[4], va_b[4];
    float ssq[4] = {0.f, 0.f, 0.f, 0.f};

#define A_ISSUE02(kt)                                                         \
    { va_a[0] = *(const float4*)(xb + (size_t)(kt) * 64);                     \
      va_a[1] = *(const float4*)(xb + (size_t)(kt) * 64 + 4);                 \
      va_a[2] = *(const float4*)(xb + (size_t)(kt) * 64 + (size_t)128 * H);   \
      va_a[3] = *(const float4*)(xb + (size_t)(kt) * 64 + (size_t)128 * H + 4); }

#define A_ISSUE13(kt)                                                         \
    { va_b[0] = *(const float4*)(xb + (size_t)(kt) * 64 + (size_t)64 * H);    \
      va_b[1] = *(const float4*)(xb + (size_t)(kt) * 64 + (size_t)64 * H + 4);\
      va_b[2] = *(const float4*)(xb + (size_t)(kt) * 64 + (size_t)192 * H);   \
      va_b[3] = *(const float4*)(xb + (size_t)(kt) * 64 + (size_t)192 * H + 4); }

#define CVT1(vlo, vhi, QS, ROW, buf)                                          \
    {                                                                         \
        float4 f0 = vlo, f1 = vhi;                                            \
        ssq[QS] += f0.x * f0.x + f0.y * f0.y + f0.z * f0.z + f0.w * f0.w;     \
        ssq[QS] += f1.x * f1.x + f1.y * f1.y + f1.z * f1.z + f1.w * f1.w;     \
        bf16x8 pk;                                                            \
        pk[0] = f2bf(f0.x); pk[1] = f2bf(f0.y); pk[2] = f2bf(f0.z);           \
        pk[3] = f2bf(f0.w); pk[4] = f2bf(f1.x); pk[5] = f2bf(f1.y);           \
        pk[6] = f2bf(f1.z); pk[7] = f2bf(f1.w);                               \
        *(bf16x8*)(smem + (size_t)(buf) * 49152 + (ROW) * 128 + awz) = pk;    \
    }

#define A_CVT02(buf) { CVT1(va_a[0], va_a[1], 0, r, buf)                      \
                       CVT1(va_a[2], va_a[3], 2, 128 + r, buf) }
#define A_CVT13(buf) { CVT1(va_b[0], va_b[1], 1, 64 + r, buf)                 \
                       CVT1(va_b[2], va_b[3], 3, 192 + r, buf) }

#define STAGE_B(buf, kt)                                                      \
    { GLOAD_LDS16(bG0 + (size_t)(kt) * 128,                                   \
                  smem + (buf) * 49152 + 32768 + tid * 16);                   \
      GLOAD_LDS16(bG1 + (size_t)(kt) * 128,                                   \
                  smem + (buf) * 49152 + 32768 + 8192 + tid * 16); }

    // ---- fragment read addressing (swizzled) ----
    const int rowA = wm * 128 + (lane & 15);
    const int rowB = wn * 32 + (lane & 15);
    const int xm = (lane & 7) << 4;
    const int c0 = (((lane >> 4) * 16)) ^ xm;
    const int c1 = (64 + ((lane >> 4) * 16)) ^ xm;

    f32x4 acc[8][2] = {};

#define MFMA16(AK0, AK1, B0, B1, MIOFF)                                       \
    _Pragma("unroll") for (int mi = 0; mi < 4; ++mi)                          \
        _Pragma("unroll") for (int ni = 0; ni < 2; ++ni)                      \
            acc[(MIOFF) + mi][ni] = __builtin_amdgcn_mfma_f32_16x16x32_bf16(  \
                AK0[mi], B0[ni], acc[(MIOFF) + mi][ni], 0, 0, 0);             \
    _Pragma("unroll") for (int mi = 0; mi < 4; ++mi)                          \
        _Pragma("unroll") for (int ni = 0; ni < 2; ++ni)                      \
            acc[(MIOFF) + mi][ni] = __builtin_amdgcn_mfma_f32_16x16x32_bf16(  \
                AK1[mi], B1[ni], acc[(MIOFF) + mi][ni], 0, 0, 0);

#define TILE(cur, kt, CARRY, DS, VM)                                          \
    {                                                                         \
        const char* aL = smem + (cur) * 49152;                                \
        const char* bL = aL + 32768;                                          \
        /* ---- P1 ---- */                                                    \
        if (CARRY) A_CVT13((cur) ^ 1);       /* kt+1 data into other buf */   \
        if (DS) A_ISSUE02((kt) + 2);                                          \
        bf16x8 a0k0[4], a0k1[4], b0[2], b1[2];                                \
        _Pragma("unroll") for (int mi = 0; mi < 4; ++mi) {                    \
            a0k0[mi] = *(const bf16x8*)(aL + (rowA + mi * 16) * 128 + c0);    \
            a0k1[mi] = *(const bf16x8*)(aL + (rowA + mi * 16) * 128 + c1);    \
        }                                                                     \
        _Pragma("unroll") for (int ni = 0; ni < 2; ++ni) {                    \
            b0[ni] = *(const bf16x8*)(bL + (rowB + ni * 16) * 128 + c0);      \
            b1[ni] = *(const bf16x8*)(bL + (rowB + ni * 16) * 128 + c1);      \
        }                                                                     \
        asm volatile("s_waitcnt lgkmcnt(8)" ::: "memory");                    \
        __builtin_amdgcn_s_barrier();                                         \
        asm volatile("s_waitcnt lgkmcnt(0)" ::: "memory");                    \
        __builtin_amdgcn_s_setprio(1);                                        \
        MFMA16(a0k0, a0k1, b0, b1, 0);                                        \
        __builtin_amdgcn_s_setprio(0);                                        \
        __builtin_amdgcn_s_barrier();                                         \
        /* ---- P2 ---- */                                                    \
        if (DS) { A_CVT02(cur); A_ISSUE13((kt) + 2); STAGE_B(cur, (kt) + 2); }\
        bf16x8 a1k0[4], a1k1[4];                                              \
        _Pragma("unroll") for (int mi = 0; mi < 4; ++mi) {                    \
            a1k0[mi] = *(const bf16x8*)(aL + (rowA + 64 + mi * 16) * 128 + c0); \
            a1k1[mi] = *(const bf16x8*)(aL + (rowA + 64 + mi * 16) * 128 + c1); \
        }                                                                     \
        __builtin_amdgcn_s_barrier();                                         \
        asm volatile("s_waitcnt lgkmcnt(0)" ::: "memory");                    \
        __builtin_amdgcn_s_setprio(1);                                        \
        MFMA16(a1k0, a1k1, b0, b1, 4);                                        \
        __builtin_amdgcn_s_setprio(0);                                        \
        asm volatile("s_waitcnt vmcnt(" VM ")" ::: "memory");                 \
        __builtin_amdgcn_sched_barrier(0);                                    \
        __builtin_amdgcn_s_barrier();                                         \
        __builtin_amdgcn_sched_barrier(0);                                    \
    }

    // ---- prologue: fully stage tiles 0 (buf0) and 1 (buf1) ----
    A_ISSUE02(0); A_ISSUE13(0); STAGE_B(0, 0);
    A_CVT02(0);   A_CVT13(0);          // auto-vmcnt waits the x loads
    A_ISSUE02(1); A_ISSUE13(1); STAGE_B(1, 1);
    A_CVT02(1);   A_CVT13(1);
    asm volatile("s_waitcnt vmcnt(2) lgkmcnt(0)" ::: "memory");  // drain B(0)
    __builtin_amdgcn_sched_barrier(0);
    __builtin_amdgcn_s_barrier();
    __builtin_amdgcn_sched_barrier(0);

    // ---- main loop ----
    TILE(0, 0, 0, 1, "6");
    TILE(1, 1, 1, 1, "6");
    for (int kt = 2; kt < NKT - 2; kt += 2) {
        TILE(0, kt, 1, 1, "6");
        TILE(1, kt + 1, 1, 1, "6");
    }
    TILE(0, NKT - 2, 1, 0, "0");       // carries cvt13 for tile 15; drains B(15)
    TILE(1, NKT - 1, 0, 0, "0");

    // ---- row scales: 8 staging lanes per row hold partial sum(x^2) ----
#pragma unroll
    for (int q = 0; q < 4; ++q) {
        float s = ssq[q];
        s += __shfl_xor(s, 1);
        s += __shfl_xor(s, 2);
        s += __shfl_xor(s, 4);
        if ((tid & 7) == 0) s_lds[q * 64 + r] = rsqrtf(s * (1.0f / H) + 1e-6f);
    }
    __syncthreads();

    // ---- epilogue: scale rows, split q/k/v regions (BN=128-aligned) ----
    const size_t QSZ = (size_t)rows * 1024;
    const size_t KSZ = (size_t)rows * 128;
    float* op;
    int ldc, cb0;
    if (nt < 8)       { op = out;             ldc = 1024; cb0 = nt * 128; }
    else if (nt == 8) { op = out + QSZ;       ldc = 128;  cb0 = 0; }
    else              { op = out + QSZ + KSZ; ldc = 128;  cb0 = 0; }

    const int rl0 = wm * 128 + ((lane >> 4) * 4);
    const size_t r0 = m0 + rl0;
    const int cc0 = cb0 + wn * 32 + (lane & 15);
#pragma unroll
    for (int mi = 0; mi < 8; ++mi)
#pragma unroll
        for (int rr = 0; rr < 4; ++rr) {
            const float sc = s_lds[rl0 + mi * 16 + rr];
#pragma unroll
            for (int ni = 0; ni < 2; ++ni)
                op[(r0 + mi * 16 + rr) * (size_t)ldc + cc0 + ni * 16] =
                    acc[mi][ni][rr] * sc;
        }
}

// ---------------------------------------------------------------------------
extern "C" void kernel_launch(void* const* d_in, const int* in_sizes, int n_in,
                              void* d_out, int out_size, void* d_ws, size_t ws_size,
                              hipStream_t stream) {
    const float* x   = (const float*)d_in[0];
    const float* lnw = (const float*)d_in[1];
    const float* wq  = (const float*)d_in[2];
    const float* wk  = (const float*)d_in[3];
    const float* wv  = (const float*)d_in[4];
    float* out = (float*)d_out;

    const int rows = in_sizes[0] / H;  // B*S = 32768

    __hip_bfloat16* Bt = (__hip_bfloat16*)d_ws;  // 1280*1024*2 = 2.62 MB

    k_wprep<<<320, 256, 0, stream>>>(wq, wk, wv, lnw, Bt);
    k_gemm<<<(rows / BM) * NTILES, 512, 0, stream>>>(x, Bt, out, rows);
}

// Round 8
// 151.721 us; speedup vs baseline: 1.5642x; 1.5642x over previous
//
#include <hip/hip_runtime.h>
#include <hip/hip_bf16.h>

typedef __attribute__((ext_vector_type(4))) float f32x4;
typedef __attribute__((ext_vector_type(8))) short bf16x8;

#define H 1024        // hidden / K
#define NTOT 1280     // nq*64 + nkv*64*2
#define BM 128
#define BN 256
#define BK 64
#define NKT 16        // H / BK
#define NTILES 5      // NTOT / BN

static __device__ __forceinline__ unsigned short f2bf(float f) {
    __hip_bfloat16 b = __float2bfloat16(f);
    return __builtin_bit_cast(unsigned short, b);
}

#define GLOAD_LDS16(g, l)                                                     \
    __builtin_amdgcn_global_load_lds(                                         \
        (const __attribute__((address_space(1))) void*)(g),                   \
        (__attribute__((address_space(3))) void*)(l), 16, 0, 0)

// ---------------------------------------------------------------------------
// Kernel 1: RMSNorm rows of x (fp32) -> h (bf16). One wave per row.
// (1+lnw) folded into weights, not here.
// ---------------------------------------------------------------------------
__global__ __launch_bounds__(256) void k_rms(const float* __restrict__ x,
                                             __hip_bfloat16* __restrict__ h) {
    const int wave = threadIdx.x >> 6;
    const int lane = threadIdx.x & 63;
    const size_t row = (size_t)blockIdx.x * 4 + wave;

    const float4* xr = (const float4*)(x + row * H);
    float4 v[4];
    float ss = 0.f;
#pragma unroll
    for (int i = 0; i < 4; ++i) {
        v[i] = xr[lane + 64 * i];
        ss += v[i].x * v[i].x + v[i].y * v[i].y + v[i].z * v[i].z + v[i].w * v[i].w;
    }
#pragma unroll
    for (int o = 1; o < 64; o <<= 1) ss += __shfl_xor(ss, o);
    const float sc = rsqrtf(ss * (1.0f / H) + 1e-6f);

    ushort4* hr = (ushort4*)(h + row * H);
#pragma unroll
    for (int i = 0; i < 4; ++i) {
        ushort4 o4;
        o4.x = f2bf(v[i].x * sc);
        o4.y = f2bf(v[i].y * sc);
        o4.z = f2bf(v[i].z * sc);
        o4.w = f2bf(v[i].w * sc);
        hr[lane + 64 * i] = o4;
    }
}

// ---------------------------------------------------------------------------
// Kernel 2: Bt[n][k] = bf16((1+lnw[k]) * W[k][n]) via LDS transpose tile.
// ---------------------------------------------------------------------------
__global__ __launch_bounds__(256) void k_wprep(const float* __restrict__ wq,
                                               const float* __restrict__ wk,
                                               const float* __restrict__ wv,
                                               const float* __restrict__ lnw,
                                               __hip_bfloat16* __restrict__ Bt) {
    __shared__ float l[64][65];
    const int t = threadIdx.x;
    const int kt = blockIdx.x & 15;          // 16 k-tiles
    const int ntl = blockIdx.x >> 4;         // 20 n-tiles
    const int k0 = kt * 64, n0 = ntl * 64;
    const float* src; int ldn, nb;
    if (n0 < 1024)      { src = wq; ldn = 1024; nb = n0; }
    else if (n0 < 1152) { src = wk; ldn = 128;  nb = n0 - 1024; }
    else                { src = wv; ldn = 128;  nb = n0 - 1152; }
    const int nl = t & 63, kl = t >> 6;
#pragma unroll
    for (int i = 0; i < 16; ++i) {
        const int k = kl + i * 4;
        l[k][nl] = (1.0f + lnw[k0 + k]) * src[(size_t)(k0 + k) * ldn + nb + nl];
    }
    __syncthreads();
    const int k2 = t & 63, n2 = t >> 6;
#pragma unroll
    for (int i = 0; i < 16; ++i) {
        const int n = n2 + i * 4;
        Bt[(size_t)(n0 + n) * 1024 + k0 + k2] = __float2bfloat16(l[k2][n]);
    }
}

// ---------------------------------------------------------------------------
// Kernel 3: GEMM out[M][1280] = h[M][1024] @ Bt^T.
// BM=128 BN=256 BK=64, 8 waves (4M x 2N), 512 thr, ring-2 LDS 96KB,
// grid 1280 = 5.0 exact CU-rounds (the R4 grid had a 3-round tail).
// R4's quadrant-phase schedule adapted: 2 phases/K-tile x 16 MFMA.
//   P1: [carry: stage B-hi(kt+1) -> other buf]  12 reads (A all + B-lo)
//       lgkm(8); BAR; lgkm(0); prio1; 16 MFMA (ni0-3); prio0; BAR
//   P2: [stage A(kt+2)+B-lo(kt+2) -> this buf]  8 reads (B-hi)
//       BAR; lgkm(0); prio1; 16 MFMA (ni4-7); prio0; vmcnt(4); BAR
// All stages land in barrier-retired regions (A & B-lo retire at P1-end,
// B-hi at P2-end). Seam vmcnt(4) keeps A/B-lo(kt+2) in flight, drains
// everything tile kt+1 needs. T2 both-sides XOR swizzle; XCD chunking
// nt-fastest (5 A-sharers co-resident per XCD -> A fetched once).
// ---------------------------------------------------------------------------
__global__ __launch_bounds__(512, 2) void k_gemm(const __hip_bfloat16* __restrict__ A,
                                                 const __hip_bfloat16* __restrict__ Bt,
                                                 float* __restrict__ out, int rows) {
    __shared__ __align__(16) char smem[98304];  // 2 bufs x (A 16KB | B 32KB)

    const int tid = threadIdx.x;
    const int lane = tid & 63;
    const int wid = tid >> 6;
    const int wm = wid >> 1;   // 0..3 (32 rows each)
    const int wn = wid & 1;    // 0..1 (128 cols each)

    // bijective XCD chunk swizzle (1280 % 8 == 0), nt fastest
    const int cpx = gridDim.x >> 3;                 // 160
    const int wg = (blockIdx.x & 7) * cpx + (blockIdx.x >> 3);
    const int nt = wg % NTILES;
    const int mt = wg / NTILES;
    const size_t m0 = (size_t)mt * BM;

    // staging geometry: thread t covers row (t>>3)+j*64, 16B at (t&7)*16,
    // source col pre-swizzled by ((row&7)<<4)  (both-sides involution)
    const int cswz = ((tid & 7) * 16) ^ (((tid >> 3) & 7) << 4);
    const char* aG = (const char*)A + (m0 + (tid >> 3)) * (size_t)(H * 2) + cswz;
    const char* bG = (const char*)Bt + ((size_t)nt * BN + (tid >> 3)) * (size_t)(H * 2) + cswz;

#define STAGE_A2(buf, kt)                                                     \
    { GLOAD_LDS16(aG + (size_t)(kt) * 128,                                    \
                  smem + (buf) * 49152 + tid * 16);                           \
      GLOAD_LDS16(aG + (size_t)(kt) * 128 + (size_t)64 * (H * 2),             \
                  smem + (buf) * 49152 + 8192 + tid * 16); }
#define STAGE_B02(buf, kt)                                                    \
    { GLOAD_LDS16(bG + (size_t)(kt) * 128,                                    \
                  smem + (buf) * 49152 + 16384 + tid * 16);                   \
      GLOAD_LDS16(bG + (size_t)(kt) * 128 + (size_t)128 * (H * 2),            \
                  smem + (buf) * 49152 + 16384 + 16384 + tid * 16); }
#define STAGE_B13(buf, kt)                                                    \
    { GLOAD_LDS16(bG + (size_t)(kt) * 128 + (size_t)64 * (H * 2),             \
                  smem + (buf) * 49152 + 16384 + 8192 + tid * 16);            \
      GLOAD_LDS16(bG + (size_t)(kt) * 128 + (size_t)192 * (H * 2),            \
                  smem + (buf) * 49152 + 16384 + 24576 + tid * 16); }

    // fragment read addressing (swizzled)
    const int rowA = wm * 32 + (lane & 15);
    const int rowB = wn * 128 + (lane & 15);
    const int xm = (lane & 7) << 4;
    const int c0 = (((lane >> 4) * 16)) ^ xm;
    const int c1 = (64 + ((lane >> 4) * 16)) ^ xm;

    f32x4 acc[2][8] = {};

#define MFMAP(AK0, AK1, B0, B1, NIOFF)                                        \
    _Pragma("unroll") for (int mi = 0; mi < 2; ++mi)                          \
        _Pragma("unroll") for (int ni = 0; ni < 4; ++ni)                      \
            acc[mi][(NIOFF) + ni] = __builtin_amdgcn_mfma_f32_16x16x32_bf16(  \
                AK0[mi], B0[ni], acc[mi][(NIOFF) + ni], 0, 0, 0);             \
    _Pragma("unroll") for (int mi = 0; mi < 2; ++mi)                          \
        _Pragma("unroll") for (int ni = 0; ni < 4; ++ni)                      \
            acc[mi][(NIOFF) + ni] = __builtin_amdgcn_mfma_f32_16x16x32_bf16(  \
                AK1[mi], B1[ni], acc[mi][(NIOFF) + ni], 0, 0, 0);

#define TILE(cur, kt, CARRY, DS, VM)                                          \
    {                                                                         \
        const char* aL = smem + (cur) * 49152;                                \
        const char* bL = aL + 16384;                                          \
        /* ---- P1 ---- */                                                    \
        if (CARRY) STAGE_B13((cur) ^ 1, (kt) + 1);                            \
        bf16x8 ak0[2], ak1[2], b0k0[4], b0k1[4];                              \
        _Pragma("unroll") for (int mi = 0; mi < 2; ++mi) {                    \
            ak0[mi] = *(const bf16x8*)(aL + (rowA + mi * 16) * 128 + c0);     \
            ak1[mi] = *(const bf16x8*)(aL + (rowA + mi * 16) * 128 + c1);     \
        }                                                                     \
        _Pragma("unroll") for (int ni = 0; ni < 4; ++ni) {                    \
            b0k0[ni] = *(const bf16x8*)(bL + (rowB + ni * 16) * 128 + c0);    \
            b0k1[ni] = *(const bf16x8*)(bL + (rowB + ni * 16) * 128 + c1);    \
        }                                                                     \
        asm volatile("s_waitcnt lgkmcnt(8)" ::: "memory");                    \
        __builtin_amdgcn_s_barrier();                                         \
        asm volatile("s_waitcnt lgkmcnt(0)" ::: "memory");                    \
        __builtin_amdgcn_s_setprio(1);                                        \
        MFMAP(ak0, ak1, b0k0, b0k1, 0);                                       \
        __builtin_amdgcn_s_setprio(0);                                        \
        __builtin_amdgcn_s_barrier();                                         \
        /* ---- P2 ---- */                                                    \
        if (DS) { STAGE_A2(cur, (kt) + 2); STAGE_B02(cur, (kt) + 2); }        \
        bf16x8 b1k0[4], b1k1[4];                                              \
        _Pragma("unroll") for (int ni = 0; ni < 4; ++ni) {                    \
            b1k0[ni] = *(const bf16x8*)(bL + (rowB + 64 + ni * 16) * 128 + c0); \
            b1k1[ni] = *(const bf16x8*)(bL + (rowB + 64 + ni * 16) * 128 + c1); \
        }                                                                     \
        __builtin_amdgcn_s_barrier();                                         \
        asm volatile("s_waitcnt lgkmcnt(0)" ::: "memory");                    \
        __builtin_amdgcn_s_setprio(1);                                        \
        MFMAP(ak0, ak1, b1k0, b1k1, 4);                                       \
        __builtin_amdgcn_s_setprio(0);                                        \
        asm volatile("s_waitcnt vmcnt(" VM ")" ::: "memory");                 \
        __builtin_amdgcn_sched_barrier(0);                                    \
        __builtin_amdgcn_s_barrier();                                         \
        __builtin_amdgcn_sched_barrier(0);                                    \
    }

    // ---- prologue: full-stage tiles 0 and 1 ----
    STAGE_A2(0, 0); STAGE_B02(0, 0); STAGE_B13(0, 0);
    STAGE_A2(1, 1); STAGE_B02(1, 1); STAGE_B13(1, 1);
    asm volatile("s_waitcnt vmcnt(6)" ::: "memory");  // tile 0 complete
    __builtin_amdgcn_sched_barrier(0);
    __builtin_amdgcn_s_barrier();
    __builtin_amdgcn_sched_barrier(0);

    // ---- main loop ----
    TILE(0, 0, 0, 1, "4");
    TILE(1, 1, 1, 1, "4");
    for (int kt = 2; kt <= 12; kt += 2) {
        TILE(0, kt, 1, 1, "4");
        TILE(1, kt + 1, 1, 1, "4");
    }
    TILE(0, 14, 1, 0, "0");
    TILE(1, 15, 0, 0, "0");

    // ---- epilogue: split q/k/v regions (128-aligned wave cols) ----
    const size_t QSZ = (size_t)rows * 1024;
    const size_t KSZ = (size_t)rows * 128;
    const int colg0 = nt * BN + wn * 128;
    float* op;
    int ldc, cb0;
    if (colg0 < 1024)      { op = out;             ldc = 1024; cb0 = colg0; }
    else if (colg0 < 1152) { op = out + QSZ;       ldc = 128;  cb0 = colg0 - 1024; }
    else                   { op = out + QSZ + KSZ; ldc = 128;  cb0 = colg0 - 1152; }

    const size_t r0 = m0 + wm * 32 + ((lane >> 4) * 4);
    const int cc0 = cb0 + (lane & 15);
#pragma unroll
    for (int mi = 0; mi < 2; ++mi)
#pragma unroll
        for (int ni = 0; ni < 8; ++ni)
#pragma unroll
            for (int r = 0; r < 4; ++r)
                op[(r0 + mi * 16 + r) * (size_t)ldc + cc0 + ni * 16] = acc[mi][ni][r];
}

// ---------------------------------------------------------------------------
extern "C" void kernel_launch(void* const* d_in, const int* in_sizes, int n_in,
                              void* d_out, int out_size, void* d_ws, size_t ws_size,
                              hipStream_t stream) {
    const float* x   = (const float*)d_in[0];
    const float* lnw = (const float*)d_in[1];
    const float* wq  = (const float*)d_in[2];
    const float* wk  = (const float*)d_in[3];
    const float* wv  = (const float*)d_in[4];
    float* out = (float*)d_out;

    const int rows = in_sizes[0] / H;  // B*S = 32768

    __hip_bfloat16* Bt = (__hip_bfloat16*)d_ws;                               // 2.62 MB
    __hip_bfloat16* h  = (__hip_bfloat16*)((char*)d_ws + (size_t)NTOT * H * 2);

    k_wprep<<<320, 256, 0, stream>>>(wq, wk, wv, lnw, Bt);
    k_rms<<<rows / 4, 256, 0, stream>>>(x, h);
    k_gemm<<<(rows / BM) * NTILES, 512, 0, stream>>>(h, Bt, out, rows);
}